// Round 14
// baseline (485.401 us; speedup 1.0000x reference)
//
#include <hip/hip_runtime.h>

#define SCAN_B 1024

using f16x8 = __attribute__((ext_vector_type(8))) _Float16;
using f32x4 = __attribute__((ext_vector_type(4))) float;
typedef _Float16 half4v __attribute__((ext_vector_type(4)));
typedef _Float16 half8v __attribute__((ext_vector_type(8)));

// ---------------- precompute kernels ----------------

// fused init: zero cnt/fillc, init scan ticket/partials, convert+transpose both weights
__global__ void init_kernel(int* __restrict__ cnt, int* __restrict__ fillc,
                            int* __restrict__ partial, int* __restrict__ ticket,
                            int N, int nb,
                            const float* __restrict__ W1, _Float16* __restrict__ W1t, int K1, int N1,
                            const float* __restrict__ W2, _Float16* __restrict__ W2t, int K2, int N2) {
  int i = blockIdx.x * blockDim.x + threadIdx.x;
  if (i < N) { cnt[i] = 0; fillc[i] = 0; }
  if (i < nb) partial[i] = -1;
  if (i == 0) *ticket = 0;
  const int n1 = K1 * N1;
  if (i < n1) {
    int k = i / N1, n = i % N1;
    W1t[(size_t)n * K1 + k] = (_Float16)W1[i];
  } else if (i < n1 + K2 * N2) {
    int j = i - n1;
    int k = j / N2, n = j % N2;
    W2t[(size_t)n * K2 + k] = (_Float16)W2[j];
  }
}

__global__ void count_kernel(const int* __restrict__ ei, int* __restrict__ cnt, int E) {
  int i = blockIdx.x * blockDim.x + threadIdx.x;
  if (i < E) atomicAdd(&cnt[ei[E + i]], 1);
}

// single-pass chained scan over (cnt[i]+1) -> exclusive rowstart; also emits dinv.
// Ticket-ordered (atomicAdd arrival order) so the predecessor a block spins on has
// already started -> resident -> forward progress guaranteed (no dispatch-order assumption).
__global__ void scan_onepass_kernel(const int* __restrict__ cnt, int* __restrict__ rowstart,
                                    float* __restrict__ dinv, int* __restrict__ ticket,
                                    int* __restrict__ partial, int n) {
  __shared__ int sm[SCAN_B];
  __shared__ int s_bid, s_prefix;
  const int t = threadIdx.x;
  if (t == 0) s_bid = atomicAdd(ticket, 1);
  __syncthreads();
  const int bid = s_bid;
  const int i = bid * SCAN_B + t;

  int c = (i < n) ? cnt[i] : 0;
  if (i < n) dinv[i] = rsqrtf((float)(c + 1));
  int v = (i < n) ? (c + 1) : 0;
  sm[t] = v;
  __syncthreads();
  for (int off = 1; off < SCAN_B; off <<= 1) {
    int x = (t >= off) ? sm[t - off] : 0;
    __syncthreads();
    if (t >= off) sm[t] += x;
    __syncthreads();
  }

  if (t == 0) {
    int prefix = 0;
    if (bid > 0) {
      int p;
      do {
        p = __hip_atomic_load(&partial[bid - 1], __ATOMIC_ACQUIRE, __HIP_MEMORY_SCOPE_AGENT);
      } while (p < 0);
      prefix = p;
    }
    __hip_atomic_store(&partial[bid], prefix + sm[SCAN_B - 1],
                       __ATOMIC_RELEASE, __HIP_MEMORY_SCOPE_AGENT);
    s_prefix = prefix;
  }
  __syncthreads();
  if (i < n) rowstart[i] = s_prefix + sm[t] - v;
}

// fused: real edges (i < E) + self edges (i >= E, n = i - E, last slot of row n)
__global__ void fillself_kernel(const int* __restrict__ ei, int* __restrict__ fillc,
                                const int* __restrict__ rowstart, const int* __restrict__ cnt,
                                const float* __restrict__ dinv, float2* __restrict__ ew,
                                int E, int N) {
  int i = blockIdx.x * blockDim.x + threadIdx.x;
  if (i < E) {
    int s = ei[i];
    int d = ei[E + i];
    int p = atomicAdd(&fillc[d], 1);
    ew[rowstart[d] + p] = make_float2(__int_as_float(s), dinv[s] * dinv[d]);
  } else if (i < E + N) {
    int n = i - E;
    float dn = dinv[n];
    ew[rowstart[n] + cnt[n]] = make_float2(__int_as_float(n), dn * dn);
  }
}

// ---------------- fp16 MFMA GEMM, 8-wave, BK=32, reg-prefetch ----------------
// C[M x N] = A[M x K] @ B[K x N], BN == N. 512 threads = 8 waves (2 x 4).
// AT = float (cvt->fp16 during staging) or _Float16 (straight 16B copies).
// B pre-transposed Wt [N][K] fp16 -> LDS. Next tile's loads issued after
// staging, drain under the MFMAs. Epilogue: per-wave LDS patch -> coalesced.

template <int BM, int BN, typename AT, typename CT>
__global__ void __launch_bounds__(512, 2)
gemm_mfma_kernel(const AT* __restrict__ A, const _Float16* __restrict__ Wt,
                 CT* __restrict__ C, int M, int K) {
  constexpr int BK   = 32;
  constexpr int LDK  = 40;                 // fp16 elems per LDS row (80B)
  constexpr int MR   = BM / 2 / 16;        // 4
  constexpr int NR   = BN / 4 / 16;        // 2 (BN=128) or 1 (BN=64)
  constexpr int N    = BN;
  constexpr int LDC  = NR * 16 + 4;        // epilogue patch row stride (floats)
  constexpr int SMA  = (BM + BN) * LDK * 2;
  constexpr int SME  = 8 * 16 * LDC * 4;
  constexpr int SMEM = SMA > SME ? SMA : SME;

  __shared__ __align__(16) char smem[SMEM];
  _Float16* Asm = (_Float16*)smem;
  _Float16* Bsm = Asm + (size_t)BM * LDK;

  const int tid  = threadIdx.x;
  const int lane = tid & 63;
  const int w    = tid >> 6;          // 0..7
  const int wm   = w >> 2;            // 0..1 (64 rows each)
  const int wn   = w & 3;             // 0..3
  const int fr   = lane & 15;
  const int fq   = lane >> 4;
  const int m0   = blockIdx.x * BM;

  constexpr bool A32 = sizeof(AT) == 4;
  const int a_c = A32 ? (tid & 7) : (tid & 3);
  const int a_m = A32 ? (tid >> 3) : (tid >> 2);
  const int br  = tid >> 2;           // B row 0..127
  const int bj  = tid & 3;            // B 16B chunk (8 fp16)

  float4 av32[2];
  uint4  av16;
  uint4  bt;

  auto loadA = [&](int kt) {
    if constexpr (A32) {
#pragma unroll
      for (int p = 0; p < 2; ++p) {
        const int gm = m0 + a_m + 64 * p;
        av32[p] = (gm < M) ? *(const float4*)&A[(size_t)gm * K + kt + 4 * a_c]
                           : make_float4(0.f, 0.f, 0.f, 0.f);
      }
    } else {
      const int gm = m0 + a_m;
      av16 = (gm < M) ? *(const uint4*)&A[(size_t)gm * K + kt + 8 * a_c]
                      : make_uint4(0u, 0u, 0u, 0u);
    }
  };
  auto loadB = [&](int kt) {
    if (tid < BN * 4) bt = *(const uint4*)&Wt[(size_t)br * K + kt + 8 * bj];
  };

  f32x4 acc[MR][NR] = {};

  loadA(0);
  loadB(0);

  for (int kt = 0; kt < K; kt += BK) {
    __syncthreads();   // previous tile's LDS frag reads complete

    // ---- A staging; B copy ----
    if constexpr (A32) {
#pragma unroll
      for (int p = 0; p < 2; ++p) {
        const int r = a_m + 64 * p;
        half4v hv = {(_Float16)av32[p].x, (_Float16)av32[p].y,
                     (_Float16)av32[p].z, (_Float16)av32[p].w};
        *(half4v*)((char*)Asm + r * (LDK * 2) + a_c * 8) = hv;
      }
    } else {
      *(uint4*)((char*)Asm + a_m * (LDK * 2) + a_c * 16) = av16;
    }
    if (tid < BN * 4) *(uint4*)((char*)Bsm + br * (LDK * 2) + 16 * bj) = bt;
    __syncthreads();

    // ---- issue next tile's loads; they drain under the MFMA section ----
    if (kt + BK < K) {
      loadA(kt + BK);
      loadB(kt + BK);
    }

    // ---- fragments + MFMA ----
    f16x8 bfrag[NR];
#pragma unroll
    for (int ni = 0; ni < NR; ++ni) {
      const int r = wn * (NR * 16) + ni * 16 + fr;
      bfrag[ni] = *(const f16x8*)((const char*)Bsm + r * (LDK * 2) + fq * 16);
    }
#pragma unroll
    for (int mi = 0; mi < MR; ++mi) {
      const int r = wm * 64 + mi * 16 + fr;
      f16x8 afrag = *(const f16x8*)((const char*)Asm + r * (LDK * 2) + fq * 16);
#pragma unroll
      for (int ni = 0; ni < NR; ++ni)
        acc[mi][ni] = __builtin_amdgcn_mfma_f32_16x16x32_f16(afrag, bfrag[ni], acc[mi][ni], 0, 0, 0);
    }
  }

  // ---- epilogue: per-wave LDS patch -> coalesced stores ----
  __syncthreads();   // all frag reads done; smem reused
  {
    float* cst = (float*)smem + (size_t)w * (16 * LDC);
    constexpr int CPR   = NR * 4;        // float4 chunks per patch row
    constexpr int EPASS = (16 * CPR + 63) / 64;
#pragma unroll
    for (int mi = 0; mi < MR; ++mi) {
#pragma unroll
      for (int ni = 0; ni < NR; ++ni)
#pragma unroll
        for (int r = 0; r < 4; ++r)
          cst[(fq * 4 + r) * LDC + ni * 16 + fr] = acc[mi][ni][r];
#pragma unroll
      for (int p = 0; p < EPASS; ++p) {
        const int idx = p * 64 + lane;
        if (idx < 16 * CPR) {
          const int row = idx / CPR;
          const int ch  = idx % CPR;
          const int gm  = m0 + wm * 64 + mi * 16 + row;
          float4 v = *(const float4*)&cst[row * LDC + ch * 4];
          if (gm < M) {
            if constexpr (sizeof(CT) == 2) {
              half4v hv = {(_Float16)v.x, (_Float16)v.y, (_Float16)v.z, (_Float16)v.w};
              *(half4v*)&C[(size_t)gm * N + wn * (NR * 16) + ch * 4] = hv;
            } else {
              *(float4*)&C[(size_t)gm * N + wn * (NR * 16) + ch * 4] = v;
            }
          }
        }
      }
    }
  }
}

// ---------------- CSR pull aggregation over fp16 rows ----------------
// Lane loads 8 halfs (16B). F=128: 16 lanes/edge, 4 slots/wave; F=64: 8 lanes/edge, 8 slots.
// Unroll x4. fp32 accumulate; output type OT = float or _Float16 (RNE).

template <int F, typename OT>
__global__ void agg_kernel(const _Float16* __restrict__ hin, const int* __restrict__ rowstart,
                           const int* __restrict__ cnt, const float2* __restrict__ ew,
                           const float* __restrict__ bias, OT* __restrict__ outp, int N) {
  constexpr int LPE = F / 8;    // lanes per edge
  constexpr int EPW = 64 / LPE; // edge slots per wave
  const int wave = (int)((blockIdx.x * (size_t)blockDim.x + threadIdx.x) >> 6);
  if (wave >= N) return;
  const int lane = threadIdx.x & 63;
  const int sub  = lane / LPE;
  const int c    = lane % LPE;
  const int n    = wave;

  const int beg = rowstart[n];
  const int end = beg + cnt[n] + 1;   // incl. self edge

  float acc[8] = {};
  int j = beg + sub;
  for (; j + 3 * EPW < end; j += 4 * EPW) {
    const float2 e0 = ew[j];
    const float2 e1 = ew[j + EPW];
    const float2 e2 = ew[j + 2 * EPW];
    const float2 e3 = ew[j + 3 * EPW];
    const half8v v0 = *(const half8v*)&hin[(size_t)__float_as_int(e0.x) * F + c * 8];
    const half8v v1 = *(const half8v*)&hin[(size_t)__float_as_int(e1.x) * F + c * 8];
    const half8v v2 = *(const half8v*)&hin[(size_t)__float_as_int(e2.x) * F + c * 8];
    const half8v v3 = *(const half8v*)&hin[(size_t)__float_as_int(e3.x) * F + c * 8];
#pragma unroll
    for (int i = 0; i < 8; ++i) {
      acc[i] = fmaf((float)v0[i], e0.y, acc[i]);
      acc[i] = fmaf((float)v1[i], e1.y, acc[i]);
      acc[i] = fmaf((float)v2[i], e2.y, acc[i]);
      acc[i] = fmaf((float)v3[i], e3.y, acc[i]);
    }
  }
  for (; j < end; j += EPW) {
    const float2 e = ew[j];
    const half8v v = *(const half8v*)&hin[(size_t)__float_as_int(e.x) * F + c * 8];
#pragma unroll
    for (int i = 0; i < 8; ++i) acc[i] = fmaf((float)v[i], e.y, acc[i]);
  }

  // reduce across edge slots
#pragma unroll
  for (int d = LPE; d < 64; d <<= 1)
#pragma unroll
    for (int i = 0; i < 8; ++i) acc[i] += __shfl_xor(acc[i], d);

  if (lane < LPE) {
    const float4 b0 = *(const float4*)&bias[c * 8];
    const float4 b1 = *(const float4*)&bias[c * 8 + 4];
    float r[8];
    r[0] = fmaxf(acc[0] + b0.x, 0.f);
    r[1] = fmaxf(acc[1] + b0.y, 0.f);
    r[2] = fmaxf(acc[2] + b0.z, 0.f);
    r[3] = fmaxf(acc[3] + b0.w, 0.f);
    r[4] = fmaxf(acc[4] + b1.x, 0.f);
    r[5] = fmaxf(acc[5] + b1.y, 0.f);
    r[6] = fmaxf(acc[6] + b1.z, 0.f);
    r[7] = fmaxf(acc[7] + b1.w, 0.f);
    if constexpr (sizeof(OT) == 2) {
      half8v hv;
#pragma unroll
      for (int i = 0; i < 8; ++i) hv[i] = (_Float16)r[i];
      *(half8v*)&outp[(size_t)n * F + c * 8] = hv;
    } else {
      *(float4*)&outp[(size_t)n * F + c * 8]     = make_float4(r[0], r[1], r[2], r[3]);
      *(float4*)&outp[(size_t)n * F + c * 8 + 4] = make_float4(r[4], r[5], r[6], r[7]);
    }
  }
}

// ---------------- launch ----------------

extern "C" void kernel_launch(void* const* d_in, const int* in_sizes, int n_in,
                              void* d_out, int out_size, void* d_ws, size_t ws_size,
                              hipStream_t stream) {
  const float* x  = (const float*)d_in[0];
  const int*   ei = (const int*)d_in[1];
  const float* W1 = (const float*)d_in[2];
  const float* b1 = (const float*)d_in[3];
  const float* W2 = (const float*)d_in[4];
  const float* b2 = (const float*)d_in[5];
  float* out = (float*)d_out;

  const int F1 = in_sizes[3];           // 128
  const int F2 = in_sizes[5];           // 64
  const int F0 = in_sizes[2] / F1;      // 512
  const int N  = in_sizes[0] / F0;      // 100000
  const int E  = in_sizes[1] / 2;       // 1600000

  char* ws = (char*)d_ws;
  size_t off = 0;
  auto alloc = [&](size_t bytes) -> void* {
    void* p = ws + off;
    off = (off + bytes + 255) & ~(size_t)255;
    return p;
  };

  int*    cnt      = (int*)alloc((size_t)N * 4);
  int*    fillc    = (int*)alloc((size_t)N * 4);
  int*    rowstart = (int*)alloc((size_t)N * 4);
  float*  dinv     = (float*)alloc((size_t)N * 4);
  const int nb     = (N + SCAN_B - 1) / SCAN_B;
  int*    partial  = (int*)alloc((size_t)nb * 4);
  int*    ticket   = (int*)alloc(256);
  float2* ew       = (float2*)alloc(((size_t)E + N) * 8);
  _Float16* h      = (_Float16*)alloc((size_t)N * F1 * 2);  // fp16 GEMM1 out
  _Float16* h1     = (_Float16*)alloc((size_t)N * F1 * 2);  // fp16 agg1 out
  _Float16* h2     = h;  // fp16 GEMM2 out, reuses h (dead after agg1)
  _Float16* W1t    = (_Float16*)alloc((size_t)F0 * F1 * 2);
  _Float16* W2t    = (_Float16*)alloc((size_t)F1 * F2 * 2);

  // 1. fused init: zero cnt/fillc, scan ticket/partials, weight convert+transpose
  init_kernel<<<(N + 255) / 256, 256, 0, stream>>>(cnt, fillc, partial, ticket, N, nb,
                                                   W1, W1t, F0, F1, W2, W2t, F1, F2);
  // 2. in-degree count
  count_kernel<<<(E + 255) / 256, 256, 0, stream>>>(ei, cnt, E);
  // 3. single-pass chained scan (rowstart, dinv)
  scan_onepass_kernel<<<nb, SCAN_B, 0, stream>>>(cnt, rowstart, dinv, ticket, partial, N);
  // 4. CSR fill (real + self edges)
  fillself_kernel<<<(E + N + 255) / 256, 256, 0, stream>>>(ei, fillc, rowstart, cnt, dinv, ew, E, N);

  // 5-6. layer 1: h = fp16(x@W1) ; h1 = fp16(relu(agg(h) + b1))
  gemm_mfma_kernel<128, 128, float, _Float16><<<(N + 127) / 128, 512, 0, stream>>>(x, W1t, h, N, F0);
  {
    const long blocks = ((long)N * 64 + 255) / 256;
    agg_kernel<128, _Float16><<<(int)blocks, 256, 0, stream>>>(h, rowstart, cnt, ew, b1, h1, N);
  }

  // 7-8. layer 2: h2 = fp16(h1@W2) ; out = relu(agg(h2) + b2)  (fp32)
  gemm_mfma_kernel<128, 64, _Float16, _Float16><<<(N + 127) / 128, 512, 0, stream>>>(h1, W2t, h2, N, F1);
  {
    const long blocks = ((long)N * 64 + 255) / 256;
    agg_kernel<64, float><<<(int)blocks, 256, 0, stream>>>(h2, rowstart, cnt, ew, b2, out, N);
  }
}

// Round 16
// 345.109 us; speedup vs baseline: 1.4065x; 1.4065x over previous
//
#include <hip/hip_runtime.h>

#define SCAN_B 1024

using f16x8 = __attribute__((ext_vector_type(8))) _Float16;
using f32x4 = __attribute__((ext_vector_type(4))) float;
typedef _Float16 half4v __attribute__((ext_vector_type(4)));
typedef _Float16 half8v __attribute__((ext_vector_type(8)));

// ---------------- precompute kernels ----------------

// fused init: zero cnt/fillc + convert+transpose both weights.
// GRID MUST COVER max(N, K1*N1 + K2*N2) elements (r15 bug: grid < N left cnt poisoned).
__global__ void init_kernel(int* __restrict__ cnt, int* __restrict__ fillc, int N,
                            const float* __restrict__ W1, _Float16* __restrict__ W1t, int K1, int N1,
                            const float* __restrict__ W2, _Float16* __restrict__ W2t, int K2, int N2) {
  int i = blockIdx.x * blockDim.x + threadIdx.x;
  if (i < N) { cnt[i] = 0; fillc[i] = 0; }
  const int n1 = K1 * N1;
  if (i < n1) {
    int k = i / N1, n = i % N1;
    W1t[(size_t)n * K1 + k] = (_Float16)W1[i];
  } else if (i < n1 + K2 * N2) {
    int j = i - n1;
    int k = j / N2, n = j % N2;
    W2t[(size_t)n * K2 + k] = (_Float16)W2[j];
  }
}

__global__ void count_kernel(const int* __restrict__ ei, int* __restrict__ cnt, int E) {
  int i = blockIdx.x * blockDim.x + threadIdx.x;
  if (i < E) atomicAdd(&cnt[ei[E + i]], 1);
}

// scan over (cnt[i] + 1) (row length incl. self edge); also emits dinv = rsqrt(deg)
__global__ void scan1_kernel(const int* __restrict__ cnt, int* __restrict__ rowstart,
                             int* __restrict__ bsum, float* __restrict__ dinv, int n) {
  __shared__ int sm[SCAN_B];
  const int t = threadIdx.x;
  const int i = blockIdx.x * SCAN_B + t;
  int c = (i < n) ? cnt[i] : 0;
  if (i < n) dinv[i] = rsqrtf((float)(c + 1));
  int v = (i < n) ? (c + 1) : 0;
  sm[t] = v;
  __syncthreads();
  for (int off = 1; off < SCAN_B; off <<= 1) {
    int x = (t >= off) ? sm[t - off] : 0;
    __syncthreads();
    if (t >= off) sm[t] += x;
    __syncthreads();
  }
  if (i < n) rowstart[i] = sm[t] - v;
  if (t == SCAN_B - 1) bsum[blockIdx.x] = sm[t];
}

__global__ void scan2_kernel(int* __restrict__ bsum, int nb) {
  __shared__ int sm[SCAN_B];
  const int t = threadIdx.x;
  int v = (t < nb) ? bsum[t] : 0;
  sm[t] = v;
  __syncthreads();
  for (int off = 1; off < SCAN_B; off <<= 1) {
    int x = (t >= off) ? sm[t - off] : 0;
    __syncthreads();
    if (t >= off) sm[t] += x;
    __syncthreads();
  }
  if (t < nb) bsum[t] = sm[t] - v;
}

__global__ void scan3_kernel(int* __restrict__ rowstart, const int* __restrict__ bsum, int n) {
  int i = blockIdx.x * blockDim.x + threadIdx.x;
  if (i < n) rowstart[i] += bsum[i / SCAN_B];
}

// fused: real edges (i < E) + self edges (i >= E, n = i - E, last slot of row n)
__global__ void fillself_kernel(const int* __restrict__ ei, int* __restrict__ fillc,
                                const int* __restrict__ rowstart, const int* __restrict__ cnt,
                                const float* __restrict__ dinv, float2* __restrict__ ew,
                                int E, int N) {
  int i = blockIdx.x * blockDim.x + threadIdx.x;
  if (i < E) {
    int s = ei[i];
    int d = ei[E + i];
    int p = atomicAdd(&fillc[d], 1);
    ew[rowstart[d] + p] = make_float2(__int_as_float(s), dinv[s] * dinv[d]);
  } else if (i < E + N) {
    int n = i - E;
    float dn = dinv[n];
    ew[rowstart[n] + cnt[n]] = make_float2(__int_as_float(n), dn * dn);
  }
}

// ---------------- fp16 MFMA GEMM, 8-wave, BK=32, reg-prefetch ----------------
// C[M x N] = A[M x K] @ B[K x N], BN == N. 512 threads = 8 waves (2 x 4).
// AT = float (cvt->fp16 during staging) or _Float16 (straight 16B copies).
// B pre-transposed Wt [N][K] fp16 -> LDS. Next tile's loads issued after
// staging, drain under the MFMAs. Epilogue: per-wave LDS patch -> coalesced.

template <int BM, int BN, typename AT, typename CT>
__global__ void __launch_bounds__(512, 2)
gemm_mfma_kernel(const AT* __restrict__ A, const _Float16* __restrict__ Wt,
                 CT* __restrict__ C, int M, int K) {
  constexpr int BK   = 32;
  constexpr int LDK  = 40;                 // fp16 elems per LDS row (80B)
  constexpr int MR   = BM / 2 / 16;        // 4
  constexpr int NR   = BN / 4 / 16;        // 2 (BN=128) or 1 (BN=64)
  constexpr int N    = BN;
  constexpr int LDC  = NR * 16 + 4;        // epilogue patch row stride (floats)
  constexpr int SMA  = (BM + BN) * LDK * 2;
  constexpr int SME  = 8 * 16 * LDC * 4;
  constexpr int SMEM = SMA > SME ? SMA : SME;

  __shared__ __align__(16) char smem[SMEM];
  _Float16* Asm = (_Float16*)smem;
  _Float16* Bsm = Asm + (size_t)BM * LDK;

  const int tid  = threadIdx.x;
  const int lane = tid & 63;
  const int w    = tid >> 6;          // 0..7
  const int wm   = w >> 2;            // 0..1 (64 rows each)
  const int wn   = w & 3;             // 0..3
  const int fr   = lane & 15;
  const int fq   = lane >> 4;
  const int m0   = blockIdx.x * BM;

  constexpr bool A32 = sizeof(AT) == 4;
  const int a_c = A32 ? (tid & 7) : (tid & 3);
  const int a_m = A32 ? (tid >> 3) : (tid >> 2);
  const int br  = tid >> 2;           // B row 0..127
  const int bj  = tid & 3;            // B 16B chunk (8 fp16)

  float4 av32[2];
  uint4  av16;
  uint4  bt;

  auto loadA = [&](int kt) {
    if constexpr (A32) {
#pragma unroll
      for (int p = 0; p < 2; ++p) {
        const int gm = m0 + a_m + 64 * p;
        av32[p] = (gm < M) ? *(const float4*)&A[(size_t)gm * K + kt + 4 * a_c]
                           : make_float4(0.f, 0.f, 0.f, 0.f);
      }
    } else {
      const int gm = m0 + a_m;
      av16 = (gm < M) ? *(const uint4*)&A[(size_t)gm * K + kt + 8 * a_c]
                      : make_uint4(0u, 0u, 0u, 0u);
    }
  };
  auto loadB = [&](int kt) {
    if (tid < BN * 4) bt = *(const uint4*)&Wt[(size_t)br * K + kt + 8 * bj];
  };

  f32x4 acc[MR][NR] = {};

  loadA(0);
  loadB(0);

  for (int kt = 0; kt < K; kt += BK) {
    __syncthreads();   // previous tile's LDS frag reads complete

    // ---- A staging; B copy ----
    if constexpr (A32) {
#pragma unroll
      for (int p = 0; p < 2; ++p) {
        const int r = a_m + 64 * p;
        half4v hv = {(_Float16)av32[p].x, (_Float16)av32[p].y,
                     (_Float16)av32[p].z, (_Float16)av32[p].w};
        *(half4v*)((char*)Asm + r * (LDK * 2) + a_c * 8) = hv;
      }
    } else {
      *(uint4*)((char*)Asm + a_m * (LDK * 2) + a_c * 16) = av16;
    }
    if (tid < BN * 4) *(uint4*)((char*)Bsm + br * (LDK * 2) + 16 * bj) = bt;
    __syncthreads();

    // ---- issue next tile's loads; they drain under the MFMA section ----
    if (kt + BK < K) {
      loadA(kt + BK);
      loadB(kt + BK);
    }

    // ---- fragments + MFMA ----
    f16x8 bfrag[NR];
#pragma unroll
    for (int ni = 0; ni < NR; ++ni) {
      const int r = wn * (NR * 16) + ni * 16 + fr;
      bfrag[ni] = *(const f16x8*)((const char*)Bsm + r * (LDK * 2) + fq * 16);
    }
#pragma unroll
    for (int mi = 0; mi < MR; ++mi) {
      const int r = wm * 64 + mi * 16 + fr;
      f16x8 afrag = *(const f16x8*)((const char*)Asm + r * (LDK * 2) + fq * 16);
#pragma unroll
      for (int ni = 0; ni < NR; ++ni)
        acc[mi][ni] = __builtin_amdgcn_mfma_f32_16x16x32_f16(afrag, bfrag[ni], acc[mi][ni], 0, 0, 0);
    }
  }

  // ---- epilogue: per-wave LDS patch -> coalesced stores ----
  __syncthreads();   // all frag reads done; smem reused
  {
    float* cst = (float*)smem + (size_t)w * (16 * LDC);
    constexpr int CPR   = NR * 4;        // float4 chunks per patch row
    constexpr int EPASS = (16 * CPR + 63) / 64;
#pragma unroll
    for (int mi = 0; mi < MR; ++mi) {
#pragma unroll
      for (int ni = 0; ni < NR; ++ni)
#pragma unroll
        for (int r = 0; r < 4; ++r)
          cst[(fq * 4 + r) * LDC + ni * 16 + fr] = acc[mi][ni][r];
#pragma unroll
      for (int p = 0; p < EPASS; ++p) {
        const int idx = p * 64 + lane;
        if (idx < 16 * CPR) {
          const int row = idx / CPR;
          const int ch  = idx % CPR;
          const int gm  = m0 + wm * 64 + mi * 16 + row;
          float4 v = *(const float4*)&cst[row * LDC + ch * 4];
          if (gm < M) {
            if constexpr (sizeof(CT) == 2) {
              half4v hv = {(_Float16)v.x, (_Float16)v.y, (_Float16)v.z, (_Float16)v.w};
              *(half4v*)&C[(size_t)gm * N + wn * (NR * 16) + ch * 4] = hv;
            } else {
              *(float4*)&C[(size_t)gm * N + wn * (NR * 16) + ch * 4] = v;
            }
          }
        }
      }
    }
  }
}

// ---------------- CSR pull aggregation over fp16 rows ----------------
// Lane loads 8 halfs (16B). F=128: 16 lanes/edge, 4 slots/wave; F=64: 8 lanes/edge, 8 slots.
// Unroll x4. fp32 accumulate; output type OT = float or _Float16 (RNE).

template <int F, typename OT>
__global__ void agg_kernel(const _Float16* __restrict__ hin, const int* __restrict__ rowstart,
                           const int* __restrict__ cnt, const float2* __restrict__ ew,
                           const float* __restrict__ bias, OT* __restrict__ outp, int N) {
  constexpr int LPE = F / 8;    // lanes per edge
  constexpr int EPW = 64 / LPE; // edge slots per wave
  const int wave = (int)((blockIdx.x * (size_t)blockDim.x + threadIdx.x) >> 6);
  if (wave >= N) return;
  const int lane = threadIdx.x & 63;
  const int sub  = lane / LPE;
  const int c    = lane % LPE;
  const int n    = wave;

  const int beg = rowstart[n];
  const int end = beg + cnt[n] + 1;   // incl. self edge

  float acc[8] = {};
  int j = beg + sub;
  for (; j + 3 * EPW < end; j += 4 * EPW) {
    const float2 e0 = ew[j];
    const float2 e1 = ew[j + EPW];
    const float2 e2 = ew[j + 2 * EPW];
    const float2 e3 = ew[j + 3 * EPW];
    const half8v v0 = *(const half8v*)&hin[(size_t)__float_as_int(e0.x) * F + c * 8];
    const half8v v1 = *(const half8v*)&hin[(size_t)__float_as_int(e1.x) * F + c * 8];
    const half8v v2 = *(const half8v*)&hin[(size_t)__float_as_int(e2.x) * F + c * 8];
    const half8v v3 = *(const half8v*)&hin[(size_t)__float_as_int(e3.x) * F + c * 8];
#pragma unroll
    for (int i = 0; i < 8; ++i) {
      acc[i] = fmaf((float)v0[i], e0.y, acc[i]);
      acc[i] = fmaf((float)v1[i], e1.y, acc[i]);
      acc[i] = fmaf((float)v2[i], e2.y, acc[i]);
      acc[i] = fmaf((float)v3[i], e3.y, acc[i]);
    }
  }
  for (; j < end; j += EPW) {
    const float2 e = ew[j];
    const half8v v = *(const half8v*)&hin[(size_t)__float_as_int(e.x) * F + c * 8];
#pragma unroll
    for (int i = 0; i < 8; ++i) acc[i] = fmaf((float)v[i], e.y, acc[i]);
  }

  // reduce across edge slots
#pragma unroll
  for (int d = LPE; d < 64; d <<= 1)
#pragma unroll
    for (int i = 0; i < 8; ++i) acc[i] += __shfl_xor(acc[i], d);

  if (lane < LPE) {
    const float4 b0 = *(const float4*)&bias[c * 8];
    const float4 b1 = *(const float4*)&bias[c * 8 + 4];
    float r[8];
    r[0] = fmaxf(acc[0] + b0.x, 0.f);
    r[1] = fmaxf(acc[1] + b0.y, 0.f);
    r[2] = fmaxf(acc[2] + b0.z, 0.f);
    r[3] = fmaxf(acc[3] + b0.w, 0.f);
    r[4] = fmaxf(acc[4] + b1.x, 0.f);
    r[5] = fmaxf(acc[5] + b1.y, 0.f);
    r[6] = fmaxf(acc[6] + b1.z, 0.f);
    r[7] = fmaxf(acc[7] + b1.w, 0.f);
    if constexpr (sizeof(OT) == 2) {
      half8v hv;
#pragma unroll
      for (int i = 0; i < 8; ++i) hv[i] = (_Float16)r[i];
      *(half8v*)&outp[(size_t)n * F + c * 8] = hv;
    } else {
      *(float4*)&outp[(size_t)n * F + c * 8]     = make_float4(r[0], r[1], r[2], r[3]);
      *(float4*)&outp[(size_t)n * F + c * 8 + 4] = make_float4(r[4], r[5], r[6], r[7]);
    }
  }
}

// ---------------- launch ----------------

extern "C" void kernel_launch(void* const* d_in, const int* in_sizes, int n_in,
                              void* d_out, int out_size, void* d_ws, size_t ws_size,
                              hipStream_t stream) {
  const float* x  = (const float*)d_in[0];
  const int*   ei = (const int*)d_in[1];
  const float* W1 = (const float*)d_in[2];
  const float* b1 = (const float*)d_in[3];
  const float* W2 = (const float*)d_in[4];
  const float* b2 = (const float*)d_in[5];
  float* out = (float*)d_out;

  const int F1 = in_sizes[3];           // 128
  const int F2 = in_sizes[5];           // 64
  const int F0 = in_sizes[2] / F1;      // 512
  const int N  = in_sizes[0] / F0;      // 100000
  const int E  = in_sizes[1] / 2;       // 1600000

  char* ws = (char*)d_ws;
  size_t off = 0;
  auto alloc = [&](size_t bytes) -> void* {
    void* p = ws + off;
    off = (off + bytes + 255) & ~(size_t)255;
    return p;
  };

  int*    cnt      = (int*)alloc((size_t)N * 4);
  int*    fillc    = (int*)alloc((size_t)N * 4);
  int*    rowstart = (int*)alloc((size_t)N * 4);
  float*  dinv     = (float*)alloc((size_t)N * 4);
  const int nb     = (N + SCAN_B - 1) / SCAN_B;
  int*    bsum     = (int*)alloc((size_t)nb * 4);
  float2* ew       = (float2*)alloc(((size_t)E + N) * 8);
  _Float16* h      = (_Float16*)alloc((size_t)N * F1 * 2);  // fp16 GEMM1 out
  _Float16* h1     = (_Float16*)alloc((size_t)N * F1 * 2);  // fp16 agg1 out
  _Float16* h2     = h;  // fp16 GEMM2 out, reuses h (dead after agg1)
  _Float16* W1t    = (_Float16*)alloc((size_t)F0 * F1 * 2);
  _Float16* W2t    = (_Float16*)alloc((size_t)F1 * F2 * 2);

  // 1. fused init: zero cnt/fillc + weight convert/transpose.
  //    Grid covers max(N, weight elems) — r15's timeout was this grid sized < N
  //    (poisoned cnt -> garbage rowstart -> OOB ew writes -> hang).
  const int initElems = (N > F0 * F1 + F1 * F2) ? N : (F0 * F1 + F1 * F2);
  init_kernel<<<(initElems + 255) / 256, 256, 0, stream>>>(
      cnt, fillc, N, W1, W1t, F0, F1, W2, W2t, F1, F2);
  // 2. in-degree count
  count_kernel<<<(E + 255) / 256, 256, 0, stream>>>(ei, cnt, E);
  // 3-5. scan (rowstart, dinv)
  scan1_kernel<<<nb, SCAN_B, 0, stream>>>(cnt, rowstart, bsum, dinv, N);
  scan2_kernel<<<1, SCAN_B, 0, stream>>>(bsum, nb);
  scan3_kernel<<<(N + 255) / 256, 256, 0, stream>>>(rowstart, bsum, N);
  // 6. CSR fill (real + self edges)
  fillself_kernel<<<(E + N + 255) / 256, 256, 0, stream>>>(ei, fillc, rowstart, cnt, dinv, ew, E, N);

  // 7-8. layer 1: h = fp16(x@W1) ; h1 = fp16(relu(agg(h) + b1))
  gemm_mfma_kernel<128, 128, float, _Float16><<<(N + 127) / 128, 512, 0, stream>>>(x, W1t, h, N, F0);
  {
    const long blocks = ((long)N * 64 + 255) / 256;
    agg_kernel<128, _Float16><<<(int)blocks, 256, 0, stream>>>(h, rowstart, cnt, ew, b1, h1, N);
  }

  // 9-10. layer 2: h2 = fp16(h1@W2) ; out = relu(agg(h2) + b2)  (fp32)
  gemm_mfma_kernel<128, 64, _Float16, _Float16><<<(N + 127) / 128, 512, 0, stream>>>(h1, W2t, h2, N, F1);
  {
    const long blocks = ((long)N * 64 + 255) / 256;
    agg_kernel<64, float><<<(int)blocks, 256, 0, stream>>>(h2, rowstart, cnt, ew, b2, out, N);
  }
}

// Round 17
// 343.458 us; speedup vs baseline: 1.4133x; 1.0048x over previous
//
#include <hip/hip_runtime.h>

#define SCAN_B 1024

using f16x8 = __attribute__((ext_vector_type(8))) _Float16;
using f32x4 = __attribute__((ext_vector_type(4))) float;
typedef _Float16 half4v __attribute__((ext_vector_type(4)));
typedef _Float16 half8v __attribute__((ext_vector_type(8)));

// ---------------- precompute kernels ----------------

// fused init: zero cnt/fillc + convert+transpose both weights.
// Grid MUST cover max(N, K1*N1 + K2*N2) elements (r15 lesson).
__global__ void init_kernel(int* __restrict__ cnt, int* __restrict__ fillc, int N,
                            const float* __restrict__ W1, _Float16* __restrict__ W1t, int K1, int N1,
                            const float* __restrict__ W2, _Float16* __restrict__ W2t, int K2, int N2) {
  int i = blockIdx.x * blockDim.x + threadIdx.x;
  if (i < N) { cnt[i] = 0; fillc[i] = 0; }
  const int n1 = K1 * N1;
  if (i < n1) {
    int k = i / N1, n = i % N1;
    W1t[(size_t)n * K1 + k] = (_Float16)W1[i];
  } else if (i < n1 + K2 * N2) {
    int j = i - n1;
    int k = j / N2, n = j % N2;
    W2t[(size_t)n * K2 + k] = (_Float16)W2[j];
  }
}

__global__ void count_kernel(const int* __restrict__ ei, int* __restrict__ cnt, int E) {
  int i = blockIdx.x * blockDim.x + threadIdx.x;
  if (i < E) atomicAdd(&cnt[ei[E + i]], 1);
}

// block-local exclusive scan over (cnt[i]+1); emits dinv. Final rowstart = rowstart[i] + bsum[i>>10].
__global__ void scan1_kernel(const int* __restrict__ cnt, int* __restrict__ rowstart,
                             int* __restrict__ bsum, float* __restrict__ dinv, int n) {
  __shared__ int sm[SCAN_B];
  const int t = threadIdx.x;
  const int i = blockIdx.x * SCAN_B + t;
  int c = (i < n) ? cnt[i] : 0;
  if (i < n) dinv[i] = rsqrtf((float)(c + 1));
  int v = (i < n) ? (c + 1) : 0;
  sm[t] = v;
  __syncthreads();
  for (int off = 1; off < SCAN_B; off <<= 1) {
    int x = (t >= off) ? sm[t - off] : 0;
    __syncthreads();
    if (t >= off) sm[t] += x;
    __syncthreads();
  }
  if (i < n) rowstart[i] = sm[t] - v;
  if (t == SCAN_B - 1) bsum[blockIdx.x] = sm[t];
}

__global__ void scan2_kernel(int* __restrict__ bsum, int nb) {
  __shared__ int sm[SCAN_B];
  const int t = threadIdx.x;
  int v = (t < nb) ? bsum[t] : 0;
  sm[t] = v;
  __syncthreads();
  for (int off = 1; off < SCAN_B; off <<= 1) {
    int x = (t >= off) ? sm[t - off] : 0;
    __syncthreads();
    if (t >= off) sm[t] += x;
    __syncthreads();
  }
  if (t < nb) bsum[t] = sm[t] - v;
}

// fused CSR fill: real edges (i < E) + self edges (i >= E). rowstart finalized inline via bsum.
__global__ void fillself_kernel(const int* __restrict__ ei, int* __restrict__ fillc,
                                const int* __restrict__ rowstart, const int* __restrict__ bsum,
                                const int* __restrict__ cnt, const float* __restrict__ dinv,
                                float2* __restrict__ ew, int E, int N) {
  int i = blockIdx.x * blockDim.x + threadIdx.x;
  if (i < E) {
    int s = ei[i];
    int d = ei[E + i];
    int p = atomicAdd(&fillc[d], 1);
    ew[rowstart[d] + bsum[d >> 10] + p] = make_float2(__int_as_float(s), dinv[s] * dinv[d]);
  } else if (i < E + N) {
    int n = i - E;
    float dn = dinv[n];
    ew[rowstart[n] + bsum[n >> 10] + cnt[n]] = make_float2(__int_as_float(n), dn * dn);
  }
}

// ---------------- fp16 MFMA GEMM, 8-wave, BK=32, double-buffered LDS ----------------
// C[M x N] = A[M x K] @ B[K x N], BN == N. 512 threads = 8 waves (2 x 4).
// One barrier per K-tile: iteration t issues next-tile loads, MFMAs from buf[t],
// stores into buf[t^1], barrier. Reads of buf[t] and writes of buf[t^1] never alias.

template <int BM, int BN, typename AT, typename CT>
__global__ void __launch_bounds__(512, 2)
gemm_mfma_kernel(const AT* __restrict__ A, const _Float16* __restrict__ Wt,
                 CT* __restrict__ C, int M, int K) {
  constexpr int BK   = 32;
  constexpr int LDK  = 40;                 // fp16 elems per LDS row (80B)
  constexpr int MR   = BM / 2 / 16;        // 4
  constexpr int NR   = BN / 4 / 16;        // 2 (BN=128) or 1 (BN=64)
  constexpr int N    = BN;
  constexpr int LDC  = NR * 16 + 4;        // epilogue patch row stride (floats)
  constexpr int SMA  = 2 * (BM + BN) * LDK * 2;
  constexpr int SME  = 8 * 16 * LDC * 4;
  constexpr int SMEM = SMA > SME ? SMA : SME;

  __shared__ __align__(16) char smem[SMEM];
  _Float16* A0 = (_Float16*)smem;
  _Float16* B0 = A0 + (size_t)BM * LDK;
  _Float16* A1 = B0 + (size_t)BN * LDK;
  _Float16* B1 = A1 + (size_t)BM * LDK;

  const int tid  = threadIdx.x;
  const int lane = tid & 63;
  const int w    = tid >> 6;          // 0..7
  const int wm   = w >> 2;            // 0..1 (64 rows each)
  const int wn   = w & 3;             // 0..3
  const int fr   = lane & 15;
  const int fq   = lane >> 4;
  const int m0   = blockIdx.x * BM;

  constexpr bool A32 = sizeof(AT) == 4;
  const int a_c = A32 ? (tid & 7) : (tid & 3);
  const int a_m = A32 ? (tid >> 3) : (tid >> 2);
  const int br  = tid >> 2;           // B row 0..127
  const int bj  = tid & 3;            // B 16B chunk (8 fp16)

  float4 av32[2];
  uint4  av16;
  uint4  bt;

  auto loadA = [&](int kt) {
    if constexpr (A32) {
#pragma unroll
      for (int p = 0; p < 2; ++p) {
        const int gm = m0 + a_m + 64 * p;
        av32[p] = (gm < M) ? *(const float4*)&A[(size_t)gm * K + kt + 4 * a_c]
                           : make_float4(0.f, 0.f, 0.f, 0.f);
      }
    } else {
      const int gm = m0 + a_m;
      av16 = (gm < M) ? *(const uint4*)&A[(size_t)gm * K + kt + 8 * a_c]
                      : make_uint4(0u, 0u, 0u, 0u);
    }
  };
  auto loadB = [&](int kt) {
    if (tid < BN * 4) bt = *(const uint4*)&Wt[(size_t)br * K + kt + 8 * bj];
  };
  auto storeAB = [&](_Float16* Asm, _Float16* Bsm) {
    if constexpr (A32) {
#pragma unroll
      for (int p = 0; p < 2; ++p) {
        const int r = a_m + 64 * p;
        half4v hv = {(_Float16)av32[p].x, (_Float16)av32[p].y,
                     (_Float16)av32[p].z, (_Float16)av32[p].w};
        *(half4v*)((char*)Asm + r * (LDK * 2) + a_c * 8) = hv;
      }
    } else {
      *(uint4*)((char*)Asm + a_m * (LDK * 2) + a_c * 16) = av16;
    }
    if (tid < BN * 4) *(uint4*)((char*)Bsm + br * (LDK * 2) + 16 * bj) = bt;
  };

  f32x4 acc[MR][NR] = {};

  loadA(0);
  loadB(0);
  storeAB(A0, B0);
  __syncthreads();

  int buf = 0;
  for (int kt = 0; kt < K; kt += BK, buf ^= 1) {
    const _Float16* Ac = buf ? A1 : A0;
    const _Float16* Bc = buf ? B1 : B0;
    _Float16* An = buf ? A0 : A1;
    _Float16* Bn = buf ? B0 : B1;
    const bool more = (kt + BK < K);

    // ---- issue next tile's global loads; they drain under the MFMAs ----
    if (more) {
      loadA(kt + BK);
      loadB(kt + BK);
    }

    // ---- fragments + MFMA from current buffer ----
    f16x8 bfrag[NR];
#pragma unroll
    for (int ni = 0; ni < NR; ++ni) {
      const int r = wn * (NR * 16) + ni * 16 + fr;
      bfrag[ni] = *(const f16x8*)((const char*)Bc + r * (LDK * 2) + fq * 16);
    }
#pragma unroll
    for (int mi = 0; mi < MR; ++mi) {
      const int r = wm * 64 + mi * 16 + fr;
      f16x8 afrag = *(const f16x8*)((const char*)Ac + r * (LDK * 2) + fq * 16);
#pragma unroll
      for (int ni = 0; ni < NR; ++ni)
        acc[mi][ni] = __builtin_amdgcn_mfma_f32_16x16x32_f16(afrag, bfrag[ni], acc[mi][ni], 0, 0, 0);
    }

    // ---- stage next buffer; single barrier per tile ----
    if (more) {
      storeAB(An, Bn);
      __syncthreads();
    }
  }

  // ---- epilogue: per-wave LDS patch -> coalesced stores ----
  __syncthreads();   // all frag reads done; smem reused
  {
    float* cst = (float*)smem + (size_t)w * (16 * LDC);
    constexpr int CPR   = NR * 4;        // float4 chunks per patch row
    constexpr int EPASS = (16 * CPR + 63) / 64;
#pragma unroll
    for (int mi = 0; mi < MR; ++mi) {
#pragma unroll
      for (int ni = 0; ni < NR; ++ni)
#pragma unroll
        for (int r = 0; r < 4; ++r)
          cst[(fq * 4 + r) * LDC + ni * 16 + fr] = acc[mi][ni][r];
#pragma unroll
      for (int p = 0; p < EPASS; ++p) {
        const int idx = p * 64 + lane;
        if (idx < 16 * CPR) {
          const int row = idx / CPR;
          const int ch  = idx % CPR;
          const int gm  = m0 + wm * 64 + mi * 16 + row;
          float4 v = *(const float4*)&cst[row * LDC + ch * 4];
          if (gm < M) {
            if constexpr (sizeof(CT) == 2) {
              half4v hv = {(_Float16)v.x, (_Float16)v.y, (_Float16)v.z, (_Float16)v.w};
              *(half4v*)&C[(size_t)gm * N + wn * (NR * 16) + ch * 4] = hv;
            } else {
              *(float4*)&C[(size_t)gm * N + wn * (NR * 16) + ch * 4] = v;
            }
          }
        }
      }
    }
  }
}

// ---------------- CSR pull aggregation over fp16 rows ----------------
// Lane loads 8 halfs (16B). Unroll x4. fp32 accumulate; OT = float or _Float16.
// rowstart finalized inline via bsum[n>>10].

template <int F, typename OT>
__global__ void agg_kernel(const _Float16* __restrict__ hin, const int* __restrict__ rowstart,
                           const int* __restrict__ bsum, const int* __restrict__ cnt,
                           const float2* __restrict__ ew, const float* __restrict__ bias,
                           OT* __restrict__ outp, int N) {
  constexpr int LPE = F / 8;    // lanes per edge
  constexpr int EPW = 64 / LPE; // edge slots per wave
  const int wave = (int)((blockIdx.x * (size_t)blockDim.x + threadIdx.x) >> 6);
  if (wave >= N) return;
  const int lane = threadIdx.x & 63;
  const int sub  = lane / LPE;
  const int c    = lane % LPE;
  const int n    = wave;

  const int beg = rowstart[n] + bsum[n >> 10];
  const int end = beg + cnt[n] + 1;   // incl. self edge

  float acc[8] = {};
  int j = beg + sub;
  for (; j + 3 * EPW < end; j += 4 * EPW) {
    const float2 e0 = ew[j];
    const float2 e1 = ew[j + EPW];
    const float2 e2 = ew[j + 2 * EPW];
    const float2 e3 = ew[j + 3 * EPW];
    const half8v v0 = *(const half8v*)&hin[(size_t)__float_as_int(e0.x) * F + c * 8];
    const half8v v1 = *(const half8v*)&hin[(size_t)__float_as_int(e1.x) * F + c * 8];
    const half8v v2 = *(const half8v*)&hin[(size_t)__float_as_int(e2.x) * F + c * 8];
    const half8v v3 = *(const half8v*)&hin[(size_t)__float_as_int(e3.x) * F + c * 8];
#pragma unroll
    for (int i = 0; i < 8; ++i) {
      acc[i] = fmaf((float)v0[i], e0.y, acc[i]);
      acc[i] = fmaf((float)v1[i], e1.y, acc[i]);
      acc[i] = fmaf((float)v2[i], e2.y, acc[i]);
      acc[i] = fmaf((float)v3[i], e3.y, acc[i]);
    }
  }
  for (; j < end; j += EPW) {
    const float2 e = ew[j];
    const half8v v = *(const half8v*)&hin[(size_t)__float_as_int(e.x) * F + c * 8];
#pragma unroll
    for (int i = 0; i < 8; ++i) acc[i] = fmaf((float)v[i], e.y, acc[i]);
  }

  // reduce across edge slots
#pragma unroll
  for (int d = LPE; d < 64; d <<= 1)
#pragma unroll
    for (int i = 0; i < 8; ++i) acc[i] += __shfl_xor(acc[i], d);

  if (lane < LPE) {
    const float4 b0 = *(const float4*)&bias[c * 8];
    const float4 b1 = *(const float4*)&bias[c * 8 + 4];
    float r[8];
    r[0] = fmaxf(acc[0] + b0.x, 0.f);
    r[1] = fmaxf(acc[1] + b0.y, 0.f);
    r[2] = fmaxf(acc[2] + b0.z, 0.f);
    r[3] = fmaxf(acc[3] + b0.w, 0.f);
    r[4] = fmaxf(acc[4] + b1.x, 0.f);
    r[5] = fmaxf(acc[5] + b1.y, 0.f);
    r[6] = fmaxf(acc[6] + b1.z, 0.f);
    r[7] = fmaxf(acc[7] + b1.w, 0.f);
    if constexpr (sizeof(OT) == 2) {
      half8v hv;
#pragma unroll
      for (int i = 0; i < 8; ++i) hv[i] = (_Float16)r[i];
      *(half8v*)&outp[(size_t)n * F + c * 8] = hv;
    } else {
      *(float4*)&outp[(size_t)n * F + c * 8]     = make_float4(r[0], r[1], r[2], r[3]);
      *(float4*)&outp[(size_t)n * F + c * 8 + 4] = make_float4(r[4], r[5], r[6], r[7]);
    }
  }
}

// ---------------- launch ----------------

extern "C" void kernel_launch(void* const* d_in, const int* in_sizes, int n_in,
                              void* d_out, int out_size, void* d_ws, size_t ws_size,
                              hipStream_t stream) {
  const float* x  = (const float*)d_in[0];
  const int*   ei = (const int*)d_in[1];
  const float* W1 = (const float*)d_in[2];
  const float* b1 = (const float*)d_in[3];
  const float* W2 = (const float*)d_in[4];
  const float* b2 = (const float*)d_in[5];
  float* out = (float*)d_out;

  const int F1 = in_sizes[3];           // 128
  const int F2 = in_sizes[5];           // 64
  const int F0 = in_sizes[2] / F1;      // 512
  const int N  = in_sizes[0] / F0;      // 100000
  const int E  = in_sizes[1] / 2;       // 1600000

  char* ws = (char*)d_ws;
  size_t off = 0;
  auto alloc = [&](size_t bytes) -> void* {
    void* p = ws + off;
    off = (off + bytes + 255) & ~(size_t)255;
    return p;
  };

  int*    cnt      = (int*)alloc((size_t)N * 4);
  int*    fillc    = (int*)alloc((size_t)N * 4);
  int*    rowstart = (int*)alloc((size_t)N * 4);
  float*  dinv     = (float*)alloc((size_t)N * 4);
  const int nb     = (N + SCAN_B - 1) / SCAN_B;
  int*    bsum     = (int*)alloc((size_t)nb * 4);
  float2* ew       = (float2*)alloc(((size_t)E + N) * 8);
  _Float16* h      = (_Float16*)alloc((size_t)N * F1 * 2);  // fp16 GEMM1 out
  _Float16* h1     = (_Float16*)alloc((size_t)N * F1 * 2);  // fp16 agg1 out
  _Float16* h2     = h;  // fp16 GEMM2 out, reuses h (dead after agg1)
  _Float16* W1t    = (_Float16*)alloc((size_t)F0 * F1 * 2);
  _Float16* W2t    = (_Float16*)alloc((size_t)F1 * F2 * 2);

  // 1. fused init (grid covers max(N, weight elems) — r15 lesson)
  const int initElems = (N > F0 * F1 + F1 * F2) ? N : (F0 * F1 + F1 * F2);
  init_kernel<<<(initElems + 255) / 256, 256, 0, stream>>>(
      cnt, fillc, N, W1, W1t, F0, F1, W2, W2t, F1, F2);
  // 2. in-degree count
  count_kernel<<<(E + 255) / 256, 256, 0, stream>>>(ei, cnt, E);
  // 3-4. scan (block-local rowstart + block offsets; finalized inline downstream)
  scan1_kernel<<<nb, SCAN_B, 0, stream>>>(cnt, rowstart, bsum, dinv, N);
  scan2_kernel<<<1, SCAN_B, 0, stream>>>(bsum, nb);
  // 5. CSR fill (real + self edges)
  fillself_kernel<<<(E + N + 255) / 256, 256, 0, stream>>>(ei, fillc, rowstart, bsum, cnt, dinv, ew, E, N);

  // 6-7. layer 1: h = fp16(x@W1) ; h1 = fp16(relu(agg(h) + b1))
  gemm_mfma_kernel<128, 128, float, _Float16><<<(N + 127) / 128, 512, 0, stream>>>(x, W1t, h, N, F0);
  {
    const long blocks = ((long)N * 64 + 255) / 256;
    agg_kernel<128, _Float16><<<(int)blocks, 256, 0, stream>>>(h, rowstart, bsum, cnt, ew, b1, h1, N);
  }

  // 8-9. layer 2: h2 = fp16(h1@W2) ; out = relu(agg(h2) + b2)  (fp32)
  gemm_mfma_kernel<128, 64, _Float16, _Float16><<<(N + 127) / 128, 512, 0, stream>>>(h1, W2t, h2, N, F1);
  {
    const long blocks = ((long)N * 64 + 255) / 256;
    agg_kernel<64, float><<<(int)blocks, 256, 0, stream>>>(h2, rowstart, bsum, cnt, ew, b2, out, N);
  }
}